// Round 4
// baseline (320.946 us; speedup 1.0000x reference)
//
#include <hip/hip_runtime.h>
#include <hip/hip_bf16.h>
#include <stdint.h>

#define NN 32768
#define HH 256

typedef short bf16x8 __attribute__((ext_vector_type(8)));
typedef float f32x4 __attribute__((ext_vector_type(4)));
typedef unsigned short ushort_t;
typedef unsigned short ushort8_t __attribute__((ext_vector_type(8)));
typedef unsigned short ushort4_t __attribute__((ext_vector_type(4)));

__device__ __forceinline__ ushort_t f2bf(float f) {
  union { float f; unsigned u; } v; v.f = f;
  unsigned u = v.u;
  unsigned r = (u + 0x7FFFu + ((u >> 16) & 1u)) >> 16;  // RNE (cold paths)
  return (ushort_t)r;
}
__device__ __forceinline__ float bf2f(ushort_t h) {
  union { unsigned u; float f; } v; v.u = ((unsigned)h) << 16;
  return v.f;
}
__device__ __forceinline__ float asf(unsigned u) {
  union { unsigned u; float f; } v; v.u = u; return v.f;
}
// HW packed f32->bf16 (RNE), 1 instr per 2 elems
__device__ __forceinline__ unsigned cvt_pk(float lo, float hi) {
  unsigned r;
  asm("v_cvt_pk_bf16_f32 %0, %1, %2" : "=v"(r) : "v"(lo), "v"(hi));
  return r;
}
__device__ __forceinline__ float sigmoidf_(float x) {
  float e = __builtin_amdgcn_exp2f(-1.4426950408889634f * x);
  return __builtin_amdgcn_rcpf(1.f + e);
}
__device__ __forceinline__ float tanhf_(float x) {
  float ax = fminf(fabsf(x), 15.f);
  float e = __builtin_amdgcn_exp2f(2.8853900817779268f * ax);  // exp(2ax)
  float t = (e - 1.f) * __builtin_amdgcn_rcpf(e + 1.f);
  return copysignf(t, x);
}
// XOR swizzle: 16B chunks within a 256-elem (512B) row, spread across rows&7
__device__ __forceinline__ int swz(int row, int col) {
  return row * 256 + ((((col >> 3) ^ (row & 7)) << 3) | (col & 7));
}

// ---------------- prep: weights -> bf16, transposed to [N][K] ----------------
__global__ void k_prep(const float* __restrict__ W_iou, const float* __restrict__ W_fin,
                       const float* __restrict__ W_f, const float* __restrict__ W_aggr,
                       ushort_t* __restrict__ WcatT, ushort_t* __restrict__ WfT,
                       ushort_t* __restrict__ WaggrT) {
  int tid = blockIdx.x * 256 + threadIdx.x;
  if (tid < 262144) {                       // WcatT [1024][256]
    int n = tid >> 8, k = tid & 255;
    float v = (n < 768) ? W_iou[k * 768 + n] : W_fin[k * 256 + (n - 768)];
    WcatT[tid] = f2bf(v);
  } else if (tid < 327680) {                // WfT [256][256]
    int t2 = tid - 262144; int n = t2 >> 8, k = t2 & 255;
    WfT[t2] = f2bf(W_f[k * 256 + n]);
  } else if (tid < 524288) {                // WaggrT [768][256]
    int t3 = tid - 327680; int n = t3 >> 8, k = t3 & 255;
    WaggrT[t3] = f2bf(W_aggr[k * 768 + n]);
  }
}

// ---------------- k1: iouf = x @ [W_iou | W_fin] + bias ----------------------
__global__ __launch_bounds__(256) void k_iou(
    const float* __restrict__ x, const ushort_t* __restrict__ WcatT,
    const float* __restrict__ b_iou, const float* __restrict__ b_fin,
    ushort_t* __restrict__ io_out, ushort_t* __restrict__ cau_out,
    ushort_t* __restrict__ f_out) {
  __shared__ __align__(16) ushort_t As[64 * 256];
  __shared__ __align__(16) ushort_t Bs[64 * 256];
  __shared__ float bias_s[64];
  const int tid = threadIdx.x;
  const int mt = blockIdx.x >> 2;
  const int nt = blockIdx.x & 3;

  const float4* Ag = (const float4*)(x + (size_t)mt * 64 * 256);
#pragma unroll
  for (int it = 0; it < 16; ++it) {
    int idx4 = tid + it * 256;
    float4 v = Ag[idx4];
    int row = idx4 >> 6, col = (idx4 & 63) << 2;
    uint2 b = { cvt_pk(v.x, v.y), cvt_pk(v.z, v.w) };
    *(uint2*)&As[swz(row, col)] = b;
  }

  const int lane = tid & 63, wv = tid >> 6;
  const int g = lane >> 4, r = lane & 15;
  const int wm = wv >> 1, wn = wv & 1;

  for (int s = 0; s < 4; ++s) {
    __syncthreads();
    const int ct = nt * 4 + s;  // 64-col tile index in [0,16)
    const ushort8_t* Bg = (const ushort8_t*)(WcatT + (size_t)ct * 64 * 256);
#pragma unroll
    for (int it = 0; it < 8; ++it) {
      int idx8 = tid + it * 256;
      int row = idx8 >> 5, col = (idx8 & 31) << 3;
      *(ushort8_t*)&Bs[swz(row, col)] = Bg[idx8];
    }
    if (tid < 64) {
      int c = ct * 64 + tid;
      bias_s[tid] = (c < 768) ? b_iou[c] : b_fin[c - 768];
    }
    __syncthreads();

    f32x4 acc[2][2] = {};
#pragma unroll
    for (int kb = 0; kb < 8; ++kb) {
      int kc = kb * 32 + g * 8;
      bf16x8 a0 = *(const bf16x8*)&As[swz(wm * 32 + r, kc)];
      bf16x8 a1 = *(const bf16x8*)&As[swz(wm * 32 + 16 + r, kc)];
      bf16x8 b0 = *(const bf16x8*)&Bs[swz(wn * 32 + r, kc)];
      bf16x8 b1 = *(const bf16x8*)&Bs[swz(wn * 32 + 16 + r, kc)];
      acc[0][0] = __builtin_amdgcn_mfma_f32_16x16x32_bf16(a0, b0, acc[0][0], 0, 0, 0);
      acc[0][1] = __builtin_amdgcn_mfma_f32_16x16x32_bf16(a0, b1, acc[0][1], 0, 0, 0);
      acc[1][0] = __builtin_amdgcn_mfma_f32_16x16x32_bf16(a1, b0, acc[1][0], 0, 0, 0);
      acc[1][1] = __builtin_amdgcn_mfma_f32_16x16x32_bf16(a1, b1, acc[1][1], 0, 0, 0);
    }
#pragma unroll
    for (int mi = 0; mi < 2; ++mi)
#pragma unroll
      for (int ni = 0; ni < 2; ++ni)
#pragma unroll
        for (int i = 0; i < 4; ++i) {
          int node = mt * 64 + wm * 32 + mi * 16 + g * 4 + i;
          int colL = wn * 32 + ni * 16 + r;
          int col = ct * 64 + colL;
          ushort_t hv = f2bf(acc[mi][ni][i] + bias_s[colL]);
          if (col < 512)      io_out[node * 512 + col] = hv;
          else if (col < 768) cau_out[node * 512 + (col - 256)] = hv;
          else                f_out[node * 256 + (col - 768)] = hv;
        }
  }
}

// ---------------- k2: f-path streamer, v3 ------------------------------------
// A = nh rows (LDS), B = W_f^T cols (registers, 64 VGPR). C[row=child][col].
// Each lane holds 4 children of one node in-register -> reduce = 3 adds +
// 1 shfl_xor(16). hsum computed in f32 during staging (register data) with
// shfl_xor(32); only half==0 blocks store it. 32 rows per barrier, 8 iters.
__global__ __launch_bounds__(256, 3) void k_fgate(
    const float* __restrict__ nh, const float* __restrict__ nc,
    const ushort_t* __restrict__ WfT, const float* __restrict__ b_f,
    const ushort_t* __restrict__ f_in,
    ushort_t* __restrict__ cau_out, ushort_t* __restrict__ hsum_out) {
  __shared__ __align__(16) ushort_t As[2][32 * 256];   // 16KB x2
  const int tid = threadIdx.x;
  const int b = blockIdx.x;
  const int half = (b >> 3) & 1;                 // W-col half (0/1)
  const int grp = ((b >> 4) << 3) | (b & 7);     // row group (256 rows), pairs co-XCD
  const int lane = tid & 63, wv = tid >> 6;
  const int g = lane >> 4, r = lane & 15;
  const int mb = half * 128 + wv * 32;           // wave's W-col base

  // --- W_f^T fragments as B-operand: col (mb+ct*16+r), k-slice (kb*32+g*8) ---
  bf16x8 wfrag[2][8];
#pragma unroll
  for (int ct = 0; ct < 2; ++ct)
#pragma unroll
    for (int kb = 0; kb < 8; ++kb)
      wfrag[ct][kb] = *(const bf16x8*)&WfT[(mb + ct * 16 + r) * 256 + kb * 32 + g * 8];

  float bias[2] = { b_f[mb + r], b_f[mb + 16 + r] };

  // staging map: thread = rowgrp(0..7)*32 + colgrp(0..31); 4 rows x 8 cols
  const int rowgrp = tid >> 5, colgrp = tid & 31;
  const size_t rowbase = (size_t)grp * 256;
  const float* sbase = nh + (rowbase + rowgrp * 4) * 256 + colgrp * 8;

  float4 pa[4][2];
#pragma unroll
  for (int rr = 0; rr < 4; ++rr) {
    pa[rr][0] = *(const float4*)(sbase + rr * 256);
    pa[rr][1] = *(const float4*)(sbase + rr * 256 + 4);
  }
  // stage chunk 0 (+ hsum)
  {
    ushort_t* buf = (ushort_t*)As[0];
#pragma unroll
    for (int rr = 0; rr < 4; ++rr) {
      uint4 p = { cvt_pk(pa[rr][0].x, pa[rr][0].y), cvt_pk(pa[rr][0].z, pa[rr][0].w),
                  cvt_pk(pa[rr][1].x, pa[rr][1].y), cvt_pk(pa[rr][1].z, pa[rr][1].w) };
      *(uint4*)&buf[swz(rowgrp * 4 + rr, colgrp * 8)] = p;
    }
    if (!half) {
      float ps[8];
#pragma unroll
      for (int j = 0; j < 8; ++j) {
        const float* f0 = (const float*)&pa[0][0];
        const float* f1 = (const float*)&pa[1][0];
        const float* f2 = (const float*)&pa[2][0];
        const float* f3 = (const float*)&pa[3][0];
        ps[j] = f0[j] + f1[j] + f2[j] + f3[j];
        ps[j] += __shfl_xor(ps[j], 32);
      }
      if ((rowgrp & 1) == 0) {
        int node = grp * 32 + (rowgrp >> 1);
        uint4 o = { cvt_pk(ps[0], ps[1]), cvt_pk(ps[2], ps[3]),
                    cvt_pk(ps[4], ps[5]), cvt_pk(ps[6], ps[7]) };
        *(uint4*)&hsum_out[node * 256 + colgrp * 8] = o;
      }
    }
  }
  __syncthreads();

  for (int it = 0; it < 8; ++it) {
    const ushort_t* cur = As[it & 1];
    const int nodebase = grp * 32 + it * 4;

    // prefetch next chunk
    float4 pb[4][2];
    if (it < 7) {
      const float* nb = sbase + (size_t)(it + 1) * 32 * 256;
#pragma unroll
      for (int rr = 0; rr < 4; ++rr) {
        pb[rr][0] = *(const float4*)(nb + rr * 256);
        pb[rr][1] = *(const float4*)(nb + rr * 256 + 4);
      }
    }

    // epilogue operands (issued early): nc + f_in
    float ncv[2][2][4];
    float fv[2][2];
#pragma unroll
    for (int rt = 0; rt < 2; ++rt) {
      int node = nodebase + rt * 2 + (g >> 1);
#pragma unroll
      for (int ct = 0; ct < 2; ++ct) {
        int col = mb + ct * 16 + r;
        fv[rt][ct] = bf2f(f_in[node * 256 + col]);
#pragma unroll
        for (int i = 0; i < 4; ++i)
          ncv[rt][ct][i] = nc[(rowbase + it * 32 + rt * 16 + g * 4 + i) * 256 + col];
      }
    }

    // MFMA: A = nh rows, B = W cols
    f32x4 acc[2][2] = {};
#pragma unroll
    for (int kb = 0; kb < 8; ++kb) {
      int kc = kb * 32 + g * 8;
      bf16x8 a0 = *(const bf16x8*)&cur[swz(r, kc)];
      bf16x8 a1 = *(const bf16x8*)&cur[swz(16 + r, kc)];
      acc[0][0] = __builtin_amdgcn_mfma_f32_16x16x32_bf16(a0, wfrag[0][kb], acc[0][0], 0, 0, 0);
      acc[0][1] = __builtin_amdgcn_mfma_f32_16x16x32_bf16(a0, wfrag[1][kb], acc[0][1], 0, 0, 0);
      acc[1][0] = __builtin_amdgcn_mfma_f32_16x16x32_bf16(a1, wfrag[0][kb], acc[1][0], 0, 0, 0);
      acc[1][1] = __builtin_amdgcn_mfma_f32_16x16x32_bf16(a1, wfrag[1][kb], acc[1][1], 0, 0, 0);
    }

    // stage next chunk (+ hsum)
    if (it < 7) {
      ushort_t* nxt = (ushort_t*)As[(it + 1) & 1];
#pragma unroll
      for (int rr = 0; rr < 4; ++rr) {
        uint4 p = { cvt_pk(pb[rr][0].x, pb[rr][0].y), cvt_pk(pb[rr][0].z, pb[rr][0].w),
                    cvt_pk(pb[rr][1].x, pb[rr][1].y), cvt_pk(pb[rr][1].z, pb[rr][1].w) };
        *(uint4*)&nxt[swz(rowgrp * 4 + rr, colgrp * 8)] = p;
      }
      if (!half) {
        float ps[8];
#pragma unroll
        for (int j = 0; j < 8; ++j) {
          const float* f0 = (const float*)&pb[0][0];
          const float* f1 = (const float*)&pb[1][0];
          const float* f2 = (const float*)&pb[2][0];
          const float* f3 = (const float*)&pb[3][0];
          ps[j] = f0[j] + f1[j] + f2[j] + f3[j];
          ps[j] += __shfl_xor(ps[j], 32);
        }
        if ((rowgrp & 1) == 0) {
          int node = grp * 32 + (it + 1) * 4 + (rowgrp >> 1);
          uint4 o = { cvt_pk(ps[0], ps[1]), cvt_pk(ps[2], ps[3]),
                      cvt_pk(ps[4], ps[5]), cvt_pk(ps[6], ps[7]) };
          *(uint4*)&hsum_out[node * 256 + colgrp * 8] = o;
        }
      }
    }

    // gates + f*nc + in-lane child reduce + 1 shfl
#pragma unroll
    for (int rt = 0; rt < 2; ++rt) {
      int node = nodebase + rt * 2 + (g >> 1);
#pragma unroll
      for (int ct = 0; ct < 2; ++ct) {
        float base = bias[ct] + fv[rt][ct];
        float s = 0.f;
#pragma unroll
        for (int i = 0; i < 4; ++i)
          s += sigmoidf_(acc[rt][ct][i] + base) * ncv[rt][ct][i];
        s += __shfl_xor(s, 16);
        if ((g & 1) == 0)
          cau_out[node * 512 + mb + ct * 16 + r] = (ushort_t)(cvt_pk(s, s) & 0xffffu);
      }
    }
    __syncthreads();
  }
}

// ---------------- k3: iou_aggr GEMM + node func ------------------------------
__global__ __launch_bounds__(256) void k_final(
    const ushort_t* __restrict__ hsum, const ushort_t* __restrict__ WaggrT,
    const float* __restrict__ b_iou, const float* __restrict__ b_aggr,
    const ushort_t* io_in, const ushort_t* cau_in,
    float* out_h, float* out_c) {
  __shared__ __align__(16) ushort_t As[16 * 256];
  __shared__ __align__(16) ushort_t Bs[64 * 256];
  __shared__ __align__(16) ushort_t Ios[16 * 512];
  __shared__ __align__(16) ushort_t CUs[16 * 512];
  __shared__ float bias_s[768];
  const int tid = threadIdx.x;
  const int blk = blockIdx.x;

  const ushort8_t* Ag = (const ushort8_t*)(hsum + blk * 4096);
#pragma unroll
  for (int it = 0; it < 2; ++it) {
    int idx8 = tid + it * 256;
    int row = idx8 >> 5, col = (idx8 & 31) << 3;
    *(ushort8_t*)&As[swz(row, col)] = Ag[idx8];
  }
  const ushort8_t* Ig = (const ushort8_t*)(io_in + blk * 8192);
  const ushort8_t* Cg = (const ushort8_t*)(cau_in + blk * 8192);
#pragma unroll
  for (int it = 0; it < 4; ++it) {
    int idx8 = tid + it * 256;
    ((ushort8_t*)Ios)[idx8] = Ig[idx8];
    ((ushort8_t*)CUs)[idx8] = Cg[idx8];
  }
#pragma unroll
  for (int it = 0; it < 3; ++it) {
    int c = tid + it * 256;
    bias_s[c] = b_iou[c] + b_aggr[c];
  }
  __syncthreads();

  const int lane = tid & 63, wv = tid >> 6;
  const int g = lane >> 4, r = lane & 15;
  f32x4 acc[12] = {};
#pragma unroll
  for (int t = 0; t < 12; ++t) {
    if (t) __syncthreads();
    const ushort8_t* Bg = (const ushort8_t*)(WaggrT + t * 64 * 256);
#pragma unroll
    for (int it = 0; it < 8; ++it) {
      int idx8 = tid + it * 256;
      int row = idx8 >> 5, col = (idx8 & 31) << 3;
      *(ushort8_t*)&Bs[swz(row, col)] = Bg[idx8];
    }
    __syncthreads();
#pragma unroll
    for (int kb = 0; kb < 8; ++kb) {
      int kc = kb * 32 + g * 8;
      bf16x8 a = *(const bf16x8*)&As[swz(r, kc)];
      bf16x8 b = *(const bf16x8*)&Bs[swz(wv * 16 + r, kc)];
      acc[t] = __builtin_amdgcn_mfma_f32_16x16x32_bf16(a, b, acc[t], 0, 0, 0);
    }
  }
#pragma unroll
  for (int t = 0; t < 4; ++t)
#pragma unroll
    for (int i = 0; i < 4; ++i) {
      int nl = g * 4 + i;
      int col = t * 64 + wv * 16 + r;
      float iv = acc[t][i]     + bias_s[col]       + bf2f(Ios[nl * 512 + col]);
      float ov = acc[t + 4][i] + bias_s[256 + col] + bf2f(Ios[nl * 512 + 256 + col]);
      float uv = acc[t + 8][i] + bias_s[512 + col] + bf2f(CUs[nl * 512 + 256 + col]);
      float ca = bf2f(CUs[nl * 512 + col]);
      float cn = sigmoidf_(iv) * tanhf_(uv) + ca;
      float hn = sigmoidf_(ov) * tanhf_(cn);
      int node = blk * 16 + nl;
      out_c[node * 256 + col] = cn;
      out_h[node * 256 + col] = hn;
    }
}

extern "C" void kernel_launch(void* const* d_in, const int* in_sizes, int n_in,
                              void* d_out, int out_size, void* d_ws, size_t ws_size,
                              hipStream_t stream) {
  const float* x      = (const float*)d_in[0];
  const float* nh     = (const float*)d_in[1];
  const float* nc     = (const float*)d_in[2];
  const float* W_iou  = (const float*)d_in[3];
  const float* b_iou  = (const float*)d_in[4];
  const float* W_fin  = (const float*)d_in[5];
  const float* b_fin  = (const float*)d_in[6];
  const float* W_f    = (const float*)d_in[7];
  const float* b_f    = (const float*)d_in[8];
  const float* W_aggr = (const float*)d_in[9];
  const float* b_aggr = (const float*)d_in[10];

  char* ws = (char*)d_ws;
  ushort_t* WcatT  = (ushort_t*)ws;                                  // 512 KB
  ushort_t* WfT    = (ushort_t*)(ws + (512 << 10));                  // 128 KB
  ushort_t* WaggrT = (ushort_t*)(ws + (640 << 10));                  // 384 KB
  ushort_t* f_in   = (ushort_t*)(ws + (1 << 20));                    // 16 MB
  ushort_t* hsum   = (ushort_t*)(ws + (1 << 20) + (16 << 20));       // 16 MB

  float* out_h = (float*)d_out;
  float* out_c = out_h + (size_t)NN * HH;
  ushort_t* io_v  = (ushort_t*)out_h;   // per node: [i 256 | o 256] bf16
  ushort_t* cau_v = (ushort_t*)out_c;   // per node: [c_aggr 256 | u 256] bf16

  k_prep<<<2048, 256, 0, stream>>>(W_iou, W_fin, W_f, W_aggr, WcatT, WfT, WaggrT);
  k_iou<<<2048, 256, 0, stream>>>(x, WcatT, b_iou, b_fin, io_v, cau_v, f_in);
  k_fgate<<<2048, 256, 0, stream>>>(nh, nc, WfT, b_f, f_in, cau_v, hsum);
  k_final<<<2048, 256, 0, stream>>>(hsum, WaggrT, b_iou, b_aggr, io_v, cau_v, out_h, out_c);
}